// Round 7
// baseline (36.298 us; speedup 1.0000x reference)
//
#include <hip/hip_runtime.h>
#include <math.h>

// out[b, 0:1024]    = -0.5*z^2 - log(std) - 0.5*log(2pi),  z=(x[b,gsc[g]]-mean[g])/std[g]
// out[b, 1024:2048] = cat_logp[c, (int)x[b, csc[c]]]
// B=16384, x:[B,256] f32, NG=NC=1024, K=32.
//
// Design C (barrier-free cat phase) + NON-TEMPORAL output/x streams:
//  The 134MB output stream write-allocates through each XCD's 4MB L2,
//  evicting the 128KB clogp gather table -> every gather re-misses to L3
//  (~268MB hidden refill traffic, invisible in FETCH_SIZE). nt stores keep
//  the write stream out of L2 so the gather table stays L2-resident.
// NOTE: __builtin_nontemporal_* requires clang ext_vector_type, not the
//  HIP_vector_type float4 struct.

#define HALF_LOG_2PI 0.91893853320467274178f

typedef float f32x4 __attribute__((ext_vector_type(4)));

constexpr int BROWS   = 16384;
constexpr int FX      = 256;
constexpr int NG      = 1024;
constexpr int NC      = 1024;
constexpr int KCAT    = 32;
constexpr int OUTW    = NG + NC;   // 2048
constexpr int ROWS_PB = 16;
constexpr int NTHR    = 256;
constexpr int XPITCH  = FX + 1;    // 257: cat idx-read bank = (row + col)%32 -> spread
constexpr int CCH     = 128;       // cat cols per chunk (32 per wave)
constexpr int NCHUNK  = NC / CCH;  // 8
constexpr int TPITCH  = 36;        // wave tile pitch: 16B-aligned rows, 2-way max on write

__global__ __launch_bounds__(NTHR) void leaves_kernel(
    const float* __restrict__ x,       // [B, 256]
    const float* __restrict__ gmean,   // [1024]
    const float* __restrict__ gstd,    // [1024]
    const float* __restrict__ clogp,   // [1024, 32]
    const int*   __restrict__ gsc,     // [1024] in [0,128)
    const int*   __restrict__ csc,     // [1024] in [128,256)
    float*       __restrict__ out)     // [B, 2048]
{
    __shared__ float xs[ROWS_PB * XPITCH];            // 16448 B
    __shared__ float wt[4][ROWS_PB * TPITCH];         //  9216 B (wave-private tiles)

    const int t = threadIdx.x;
    const long long b0 = (long long)blockIdx.x * ROWS_PB;

    // ---- stage 16 x-rows (nt loads: read-once stream, keep out of L2) ----
    {
        const int r  = t >> 4;
        const int c0 = (t & 15) * 16;
        const f32x4* src = (const f32x4*)(x + (b0 + r) * FX + c0);
        float*       dst = xs + r * XPITCH + c0;
        #pragma unroll
        for (int q = 0; q < 4; ++q) {
            f32x4 v = __builtin_nontemporal_load(src + q);
            dst[q * 4 + 0] = v.x; dst[q * 4 + 1] = v.y;
            dst[q * 4 + 2] = v.z; dst[q * 4 + 3] = v.w;
        }
    }

    // ---- per-thread gaussian tables (thread owns g-cols 4t..4t+3) ----
    const int4   g4 = ((const int4*)gsc)[t];
    const float4 mu = ((const float4*)gmean)[t];
    const float4 sd = ((const float4*)gstd)[t];
    float4 is, cc;
    is.x = 1.0f / sd.x;  cc.x = -logf(sd.x) - HALF_LOG_2PI;
    is.y = 1.0f / sd.y;  cc.y = -logf(sd.y) - HALF_LOG_2PI;
    is.z = 1.0f / sd.z;  cc.z = -logf(sd.z) - HALF_LOG_2PI;
    is.w = 1.0f / sd.w;  cc.w = -logf(sd.w) - HALF_LOG_2PI;

    __syncthreads();   // the ONLY block-wide barrier

    // ---- Gaussian half: 16 rows, coalesced 1KB wave stores (nt) ----
    #pragma unroll
    for (int r = 0; r < ROWS_PB; ++r) {
        const float* xr = xs + r * XPITCH;
        f32x4 gres;
        { float z = (xr[g4.x] - mu.x) * is.x; gres.x = fmaf(-0.5f * z, z, cc.x); }
        { float z = (xr[g4.y] - mu.y) * is.y; gres.y = fmaf(-0.5f * z, z, cc.y); }
        { float z = (xr[g4.z] - mu.z) * is.z; gres.z = fmaf(-0.5f * z, z, cc.z); }
        { float z = (xr[g4.w] - mu.w) * is.w; gres.w = fmaf(-0.5f * z, z, cc.w); }
        __builtin_nontemporal_store(gres, (f32x4*)(out + (b0 + r) * OUTW) + t);
    }

    // ---- Cat half: fully wave-local, no barriers ----
    const int w    = t >> 6;
    const int l    = t & 63;
    const int grow = l & 15;          // gather mapping: lane's row
    const int gco  = l >> 4;          // 0..3: c sub-offset
    const int frow = l >> 2;          // flush mapping: lane's row
    const int fol  = l & 3;           // 0..3: which 16B of the 64B line
    float*       tile = wt[w];
    const float* xrp  = xs + grow * XPITCH;

    for (int chunk = 0; chunk < NCHUNK; ++chunk) {
        const int cb = chunk * CCH + w * 32 + gco;   // this thread's c = cb + 4j

        // gather 8 values (32 c's per wave, 512B contiguous table window per j)
        float v[8];
        #pragma unroll
        for (int j = 0; j < 8; ++j) {
            const int c = cb + j * 4;
            v[j] = clogp[c * KCAT + (int)xrp[csc[c]]];
        }

        // in-wave transpose: write (2-way max bank overlap = free)
        #pragma unroll
        for (int j = 0; j < 8; ++j)
            tile[grow * TPITCH + j * 4 + gco] = v[j];

        // read back + store: per store-instr, each of 16 rows gets one 64B segment
        const float* trow = tile + frow * TPITCH;
        float*       drow = out + (b0 + frow) * OUTW + NG + chunk * CCH + w * 32;
        #pragma unroll
        for (int q = 0; q < 2; ++q) {
            f32x4 a = *(const f32x4*)(trow + q * 16 + fol * 4);
            __builtin_nontemporal_store(a, (f32x4*)(drow + q * 16 + fol * 4));
        }
    }
}

extern "C" void kernel_launch(void* const* d_in, const int* in_sizes, int n_in,
                              void* d_out, int out_size, void* d_ws, size_t ws_size,
                              hipStream_t stream) {
    const float* x     = (const float*)d_in[0];
    const float* gmean = (const float*)d_in[1];
    const float* gstd  = (const float*)d_in[2];
    const float* clogp = (const float*)d_in[3];
    const int*   gsc   = (const int*)d_in[4];
    const int*   csc   = (const int*)d_in[5];
    float*       out   = (float*)d_out;

    leaves_kernel<<<dim3(BROWS / ROWS_PB), dim3(NTHR), 0, stream>>>(
        x, gmean, gstd, clogp, gsc, csc, out);
}

// Round 8
// 32.656 us; speedup vs baseline: 1.1115x; 1.1115x over previous
//
#include <hip/hip_runtime.h>
#include <math.h>

// out[b, 0:1024]    = -0.5*z^2 - log(std) - 0.5*log(2pi),  z=(x[b,gsc[g]]-mean[g])/std[g]
// out[b, 1024:2048] = cat_logp[c, (int)x[b, csc[c]]]
// B=16384, x:[B,256] f32, NG=NC=1024, K=32.
//
// Design D: DRAM-write-locality for the cat half.
//  Previous (30.5us plateau): cat written as 128B pieces at 8KB stride,
//  revisited 8x per row -> L2 evicts scattered lines -> HBM row-activate
//  bound (~70% write efficiency). Now: accumulate 512 cols/row in a
//  bank-swizzled LDS tile, flush row-LINEAR (1KB contiguous per wave-instr,
//  2KB per row per pass). Gather stays 16-row transposed (<=8 lines/instr);
//  32 gathers in flight per thread per pass. nt stores reverted (R7: -19%).

#define HALF_LOG_2PI 0.91893853320467274178f

typedef float f32x4 __attribute__((ext_vector_type(4)));

constexpr int BROWS   = 16384;
constexpr int FX      = 256;
constexpr int NG      = 1024;
constexpr int NC      = 1024;
constexpr int KCAT    = 32;
constexpr int OUTW    = NG + NC;   // 2048
constexpr int ROWS_PB = 16;
constexpr int NTHR    = 256;
constexpr int XPITCH  = FX + 1;    // 257
constexpr int HCOLS   = 512;       // cat cols per pass (2 passes)
constexpr int TP      = 572;       // tile pitch (floats): %4==0 (16B), %32==28 (bank spread)
// swizzled col addr within a tile row: caddr(c) = (c>>5)*36 + (c&31), max 571 < TP

__global__ __launch_bounds__(NTHR) void leaves_kernel(
    const float* __restrict__ x,       // [B, 256]
    const float* __restrict__ gmean,   // [1024]
    const float* __restrict__ gstd,    // [1024]
    const float* __restrict__ clogp,   // [1024, 32]
    const int*   __restrict__ gsc,     // [1024] in [0,128)
    const int*   __restrict__ csc,     // [1024] in [128,256)
    float*       __restrict__ out)     // [B, 2048]
{
    __shared__ float xs[ROWS_PB * XPITCH];   // 16448 B
    __shared__ float tile[ROWS_PB * TP];     // 36608 B  (total 53056 -> 3 blocks/CU)

    const int t = threadIdx.x;
    const long long b0 = (long long)blockIdx.x * ROWS_PB;

    // ---- stage 16 x-rows: thread t loads row t>>4, cols (t&15)*16..+15 ----
    {
        const int r  = t >> 4;
        const int c0 = (t & 15) * 16;
        const float* src = x + (b0 + r) * FX + c0;
        float*       dst = xs + r * XPITCH + c0;
        #pragma unroll
        for (int q = 0; q < 4; ++q) {
            float4 v = ((const float4*)src)[q];
            dst[q * 4 + 0] = v.x; dst[q * 4 + 1] = v.y;
            dst[q * 4 + 2] = v.z; dst[q * 4 + 3] = v.w;
        }
    }

    // ---- per-thread gaussian tables (thread owns g-cols 4t..4t+3) ----
    const int4   g4 = ((const int4*)gsc)[t];
    const float4 mu = ((const float4*)gmean)[t];
    const float4 sd = ((const float4*)gstd)[t];
    float4 is, cc4;
    is.x = 1.0f / sd.x;  cc4.x = -logf(sd.x) - HALF_LOG_2PI;
    is.y = 1.0f / sd.y;  cc4.y = -logf(sd.y) - HALF_LOG_2PI;
    is.z = 1.0f / sd.z;  cc4.z = -logf(sd.z) - HALF_LOG_2PI;
    is.w = 1.0f / sd.w;  cc4.w = -logf(sd.w) - HALF_LOG_2PI;

    __syncthreads();

    // ---- Gaussian half: 16 rows, row-linear 4KB bursts ----
    #pragma unroll
    for (int r = 0; r < ROWS_PB; ++r) {
        const float* xr = xs + r * XPITCH;
        float4 gres;
        { float z = (xr[g4.x] - mu.x) * is.x; gres.x = fmaf(-0.5f * z, z, cc4.x); }
        { float z = (xr[g4.y] - mu.y) * is.y; gres.y = fmaf(-0.5f * z, z, cc4.y); }
        { float z = (xr[g4.z] - mu.z) * is.z; gres.z = fmaf(-0.5f * z, z, cc4.z); }
        { float z = (xr[g4.w] - mu.w) * is.w; gres.w = fmaf(-0.5f * z, z, cc4.w); }
        ((float4*)(out + (b0 + r) * OUTW))[t] = gres;
    }

    // ---- Cat half: 2 passes of 512 cols ----
    const int w    = t >> 6;       // wave 0..3
    const int l    = t & 63;
    const int grow = l & 15;       // gather row
    const int gco  = l >> 4;       // 0..3
    const float* xrp = xs + grow * XPITCH;

    // flush mapping: per sub-step, wave-instr = 1KB contiguous in one row
    const int frsub = t >> 7;            // 0/1: row within sub-step pair
    const int fcol  = (t & 127) * 4;     // 0..508
    const int fcadr = ((fcol >> 5) * 36) + (fcol & 31);

    #pragma unroll
    for (int pass = 0; pass < 2; ++pass) {
        const int cpb = pass * HCOLS + w * 32 + gco;

        // gather 32 values (only xs/global reads; overlaps prior flush)
        float v[32];
        #pragma unroll
        for (int cc = 0; cc < 4; ++cc) {
            #pragma unroll
            for (int jj = 0; jj < 8; ++jj) {
                const int c = cpb + cc * 128 + jj * 4;
                v[cc * 8 + jj] = clogp[c * KCAT + (int)xrp[csc[c]]];
            }
        }

        __syncthreads();   // pass1: ensure pass0 flush reads are done

        // transpose-write into swizzled tile (2-way max bank overlap)
        #pragma unroll
        for (int cc = 0; cc < 4; ++cc) {
            #pragma unroll
            for (int jj = 0; jj < 8; ++jj) {
                const int C = cc * 128 + w * 32 + jj * 4 + gco;   // pass-local col
                tile[grow * TP + ((C >> 5) * 36) + (C & 31)] = v[cc * 8 + jj];
            }
        }

        __syncthreads();   // tile complete

        // flush: 8 sub-steps x 2 rows; each wave-instr 1KB contiguous in a row
        #pragma unroll
        for (int s = 0; s < 8; ++s) {
            const int r = s * 2 + frsub;
            f32x4 a = *(const f32x4*)(tile + r * TP + fcadr);
            *(f32x4*)(out + (b0 + r) * OUTW + NG + pass * HCOLS + fcol) = a;
        }
    }
}

extern "C" void kernel_launch(void* const* d_in, const int* in_sizes, int n_in,
                              void* d_out, int out_size, void* d_ws, size_t ws_size,
                              hipStream_t stream) {
    const float* x     = (const float*)d_in[0];
    const float* gmean = (const float*)d_in[1];
    const float* gstd  = (const float*)d_in[2];
    const float* clogp = (const float*)d_in[3];
    const int*   gsc   = (const int*)d_in[4];
    const int*   csc   = (const int*)d_in[5];
    float*       out   = (float*)d_out;

    leaves_kernel<<<dim3(BROWS / ROWS_PB), dim3(NTHR), 0, stream>>>(
        x, gmean, gstd, clogp, gsc, csc, out);
}